// Round 5
// baseline (129.384 us; speedup 1.0000x reference)
//
#include <hip/hip_runtime.h>
#include <hip/hip_bf16.h>

// Shapes are fixed by the problem definition.
#define B_   16
#define T_   4096
#define N_   512
#define D_   512
#define EPSF 1e-8f

typedef __attribute__((ext_vector_type(8))) short bf16x8; // 8 bf16 = 4 VGPRs
typedef __attribute__((ext_vector_type(4))) float f32x4;

// round-to-nearest-even f32 -> bf16, packed pair into one u32
__device__ __forceinline__ unsigned int pack2bf(float a, float b) {
  unsigned int ua = __float_as_uint(a);
  ua += 0x7fffu + ((ua >> 16) & 1u);
  unsigned int ub = __float_as_uint(b);
  ub += 0x7fffu + ((ub >> 16) & 1u);
  return (ua >> 16) | (ub & 0xffff0000u);
}

// async global->LDS, 16 B per lane
__device__ __forceinline__ void gload_lds16(const void* g, void* l) {
  __builtin_amdgcn_global_load_lds(
      (const __attribute__((address_space(1))) unsigned int*)g,
      (__attribute__((address_space(3))) unsigned int*)l, 16, 0, 0);
}

// ---------------------------------------------------------------------------
// Kernel A: distractor rows -> inv_nd (f32 norms) + bf16 copy (ydbf).
// ---------------------------------------------------------------------------
__global__ void rownorms_d(const float* __restrict__ yd,
                           float* __restrict__ inv_nd,
                           unsigned short* __restrict__ ydbf) {
  const int tid = threadIdx.x;
  const int g   = tid >> 4;
  const int t   = tid & 15;
  const int row = blockIdx.x * 16 + g;
  const float* dr = yd + (size_t)row * D_;
  unsigned short* ob = ydbf + (size_t)row * D_;

  float dd = 0.f;
#pragma unroll
  for (int k = 0; k < 8; ++k) {
    const int col = k * 64 + t * 4;
    float4 a = *(const float4*)(dr + col);
    dd += a.x * a.x + a.y * a.y + a.z * a.z + a.w * a.w;
    uint2 p;
    p.x = pack2bf(a.x, a.y);
    p.y = pack2bf(a.z, a.w);
    *(uint2*)(ob + col) = p;
  }
#pragma unroll
  for (int m = 1; m < 16; m <<= 1) dd += __shfl_xor(dd, m);
  if (t == 0) inv_nd[row] = 1.f / fmaxf(sqrtf(dd), EPSF);
}

// ---- staging helpers (formulas verbatim from r1/r2, verified 0-conflict) ---
__device__ __forceinline__ void stage_A(unsigned char* As,
                                        const float* __restrict__ Ab,
                                        int k0, int tid) {
#pragma unroll
  for (int j = 0; j < 4; ++j) {
    const int g   = j * 512 + tid;        // float4 0..2047
    const int row = g >> 4;               // 16 float4 per 64-col row
    const int c4  = g & 15;
    const float4 va = *(const float4*)(Ab + (size_t)row * D_ + k0 + (c4 << 2));
    const int off = (row << 7) + ((((c4 >> 1) ^ (row & 7))) << 4) + ((c4 & 1) << 3);
    uint2 pa;
    pa.x = pack2bf(va.x, va.y);
    pa.y = pack2bf(va.z, va.w);
    *(uint2*)(As + off) = pa;
  }
}

__device__ __forceinline__ void stage_B(unsigned char* Bs,
                                        const unsigned short* __restrict__ Bb,
                                        int h, int k0, int tid) {
#pragma unroll
  for (int j = 0; j < 4; ++j) {
    const int g   = j * 512 + tid;          // chunk 0..2047 (16 B each)
    const int row = g >> 3;                 // local row 0..255
    const int sch = (g & 7) ^ (row & 7);    // inverse-swizzled source chunk
    gload_lds16(Bb + (size_t)(h * 256 + row) * D_ + k0 + (sch << 3),
                Bs + (g << 4));
  }
}

// ---------------------------------------------------------------------------
// Kernel B (mega-fusion, r5): one block per (mt,b) = 128-row band.
// N processed in two sequential 256-col halves -> acc[4][4] (64 regs),
// Bs 32 KB, total LDS ~50.5 KB, __launch_bounds__(512,4) -> 2 blocks/CU
// (r4 was 1 block/CU, occupancy 23%, pure barrier-serialization-bound).
// ---------------------------------------------------------------------------
__launch_bounds__(512, 4)
__global__ void fused_ct(const float* __restrict__ c,
                         const float* __restrict__ yt,
                         const unsigned short* __restrict__ ydbf,
                         const float* __restrict__ inv_nd,
                         float* __restrict__ rt,
                         float* __restrict__ S) {
  __shared__ __align__(16) unsigned char As[128 * 64 * 2];  // 16 KB
  __shared__ __align__(16) unsigned char Bs[256 * 64 * 2];  // 32 KB
  __shared__ float s_invc[128];
  __shared__ float s_invd[512];

  const int mt = blockIdx.x;
  const int b  = blockIdx.y;
  const int tid  = threadIdx.x;
  const int lane = tid & 63;
  const int w    = tid >> 6;
  const int wm   = w >> 2, wn = w & 3;   // 2 x 4 waves over 128 x 256 half

  const float* Ab = c  + ((size_t)b * T_ + (size_t)mt * 128) * D_;
  const float* Tb = yt + ((size_t)b * T_ + (size_t)mt * 128) * D_;
  const unsigned short* Bb = ydbf + (size_t)b * N_ * D_;

  // prefetch Bs(h=0,k0=0): hides ydbf latency under phase 1
  stage_B(Bs, Bb, 0, 0, tid);

  s_invd[tid] = inv_nd[b * N_ + tid];

  // ---- phase 1: stats over the 128-row band (16 thr/row) ----
  {
    const int t  = tid & 15;
    const int rg = tid >> 4;                // 32 row-groups
#pragma unroll
    for (int rp = 0; rp < 4; ++rp) {
      const int row = rp * 32 + rg;
      const float* cr = Ab + (size_t)row * D_;
      const float* tr = Tb + (size_t)row * D_;
      float cc = 0.f, tt = 0.f, ct = 0.f;
#pragma unroll
      for (int k = 0; k < 8; ++k) {
        const int col = k * 64 + t * 4;
        float4 a  = *(const float4*)(cr + col);
        float4 bb = *(const float4*)(tr + col);
        cc += a.x * a.x + a.y * a.y + a.z * a.z + a.w * a.w;
        tt += bb.x * bb.x + bb.y * bb.y + bb.z * bb.z + bb.w * bb.w;
        ct += a.x * bb.x + a.y * bb.y + a.z * bb.z + a.w * bb.w;
      }
#pragma unroll
      for (int m = 1; m < 16; m <<= 1) {
        cc += __shfl_xor(cc, m);
        tt += __shfl_xor(tt, m);
        ct += __shfl_xor(ct, m);
      }
      if (t == 0) {
        float nc = fmaxf(sqrtf(cc), EPSF);
        float nt = fmaxf(sqrtf(tt), EPSF);
        s_invc[row] = 1.f / nc;
        rt[b * T_ + mt * 128 + row] = ct / (nt * nc);
      }
    }
  }

  // ---- phases 2+3: two N-halves, each 8 K-iters then exp epilogue ----
  for (int h = 0; h < 2; ++h) {
    f32x4 acc[4][4] = {};

    for (int k0i = 0; k0i < 8; ++k0i) {
      const int k0 = k0i * 64;
      stage_A(As, Ab, k0, tid);
      if (k0i > 0) stage_B(Bs, Bb, h, k0, tid);  // (h,0) prefetched earlier
      __syncthreads();

#pragma unroll
      for (int ks = 0; ks < 2; ++ks) {
        bf16x8 af[4], bfr[4];
#pragma unroll
        for (int i = 0; i < 4; ++i) {
          const int ar  = wm * 64 + i * 16 + (lane & 15);
          const int ach = (ks * 4 + (lane >> 4)) ^ (ar & 7);
          af[i] = *(const bf16x8*)(As + (ar << 7) + (ach << 4));
          const int br  = wn * 64 + i * 16 + (lane & 15);
          const int bch = (ks * 4 + (lane >> 4)) ^ (br & 7);
          bfr[i] = *(const bf16x8*)(Bs + (br << 7) + (bch << 4));
        }
#pragma unroll
        for (int mi = 0; mi < 4; ++mi)
#pragma unroll
          for (int ni = 0; ni < 4; ++ni)
            acc[mi][ni] = __builtin_amdgcn_mfma_f32_16x16x32_bf16(
                af[mi], bfr[ni], acc[mi][ni], 0, 0, 0);
      }
      __syncthreads();
    }

    // issue next half's first B-stage before the epilogue (epilogue is
    // register/LDS-stats only -> gload latency hides under it)
    if (h == 0) stage_B(Bs, Bb, 1, 0, tid);

    // ---- exp epilogue for this 256-col half ----
    float invd[4];
#pragma unroll
    for (int ni = 0; ni < 4; ++ni)
      invd[ni] = s_invd[h * 256 + wn * 64 + ni * 16 + (lane & 15)];

#pragma unroll
    for (int mi = 0; mi < 4; ++mi) {
      const int t0l = wm * 64 + mi * 16 + ((lane >> 4) << 2);  // local row
#pragma unroll
      for (int r = 0; r < 4; ++r) {
        const float invc = s_invc[t0l + r];
        float s = 0.f;
#pragma unroll
        for (int ni = 0; ni < 4; ++ni)
          s += __expf(acc[mi][ni][r] * invc * invd[ni]);
        s += __shfl_xor(s, 1);
        s += __shfl_xor(s, 2);
        s += __shfl_xor(s, 4);
        s += __shfl_xor(s, 8);
        if ((lane & 15) == 0)
          atomicAdd(&S[b * T_ + mt * 128 + t0l + r], s);
      }
    }
  }
}

// ---------------------------------------------------------------------------
// Kernel C: loss = sum_{b,t} log(S + exp(r_t)) - r_t
// ---------------------------------------------------------------------------
__global__ void final_loss(const float* __restrict__ S,
                           const float* __restrict__ rt,
                           float* __restrict__ out) {
  const int tid = threadIdx.x;
  float sum = 0.f;
  for (int i = blockIdx.x * blockDim.x + tid; i < B_ * T_;
       i += gridDim.x * blockDim.x) {
    const float r = rt[i];
    sum += logf(S[i] + __expf(r)) - r;
  }
#pragma unroll
  for (int m = 32; m; m >>= 1) sum += __shfl_xor(sum, m);
  __shared__ float ws[4];
  if ((tid & 63) == 0) ws[tid >> 6] = sum;
  __syncthreads();
  if (tid == 0) atomicAdd(out, ws[0] + ws[1] + ws[2] + ws[3]);
}

// ---------------------------------------------------------------------------
extern "C" void kernel_launch(void* const* d_in, const int* in_sizes, int n_in,
                              void* d_out, int out_size, void* d_ws, size_t ws_size,
                              hipStream_t stream) {
  (void)in_sizes; (void)n_in; (void)out_size; (void)ws_size;
  const float* c  = (const float*)d_in[0];
  const float* yt = (const float*)d_in[1];
  const float* yd = (const float*)d_in[2];
  float* out = (float*)d_out;

  // ws layout: [ydbf: B*N*D u16][rt: B*T f][inv_nd: B*N f][S: B*T f]
  const size_t ydbf_n = (size_t)B_ * N_ * D_;   // 4.2M u16 = 8 MiB
  unsigned short* ydbf = (unsigned short*)d_ws;
  float* rt     = (float*)(ydbf + ydbf_n);      // B*T
  float* inv_nd = rt + B_ * T_;                 // B*N
  float* S      = inv_nd + B_ * N_;             // B*T

  hipMemsetAsync(S, 0, (size_t)B_ * T_ * sizeof(float), stream);
  hipMemsetAsync(out, 0, sizeof(float), stream);

  rownorms_d<<<B_ * N_ / 16, 256, 0, stream>>>(yd, inv_nd, ydbf);

  dim3 gF(T_ / 128, B_);   // (32, 16) = 512 blocks, 512 threads
  fused_ct<<<gF, 512, 0, stream>>>(c, yt, ydbf, inv_nd, rt, S);

  final_loss<<<64, 256, 0, stream>>>(S, rt, out);
}

// Round 6
// 93.041 us; speedup vs baseline: 1.3906x; 1.3906x over previous
//
#include <hip/hip_runtime.h>
#include <hip/hip_bf16.h>

// Shapes are fixed by the problem definition.
#define B_   16
#define T_   4096
#define N_   512
#define D_   512
#define EPSF 1e-8f

typedef __attribute__((ext_vector_type(8))) short bf16x8; // 8 bf16 = 4 VGPRs
typedef __attribute__((ext_vector_type(4))) float f32x4;

// round-to-nearest-even f32 -> bf16, packed pair into one u32
__device__ __forceinline__ unsigned int pack2bf(float a, float b) {
  unsigned int ua = __float_as_uint(a);
  ua += 0x7fffu + ((ua >> 16) & 1u);
  unsigned int ub = __float_as_uint(b);
  ub += 0x7fffu + ((ub >> 16) & 1u);
  return (ua >> 16) | (ub & 0xffff0000u);
}

// async global->LDS, 16 B per lane
__device__ __forceinline__ void gload_lds16(const void* g, void* l) {
  __builtin_amdgcn_global_load_lds(
      (const __attribute__((address_space(1))) unsigned int*)g,
      (__attribute__((address_space(3))) unsigned int*)l, 16, 0, 0);
}

// ---------------------------------------------------------------------------
// Kernel A: distractor rows -> inv_nd (f32 norms) + bf16 copy (ydbf).
// ---------------------------------------------------------------------------
__global__ void rownorms_d(const float* __restrict__ yd,
                           float* __restrict__ inv_nd,
                           unsigned short* __restrict__ ydbf) {
  const int tid = threadIdx.x;
  const int g   = tid >> 4;
  const int t   = tid & 15;
  const int row = blockIdx.x * 16 + g;
  const float* dr = yd + (size_t)row * D_;
  unsigned short* ob = ydbf + (size_t)row * D_;

  float dd = 0.f;
#pragma unroll
  for (int k = 0; k < 8; ++k) {
    const int col = k * 64 + t * 4;
    float4 a = *(const float4*)(dr + col);
    dd += a.x * a.x + a.y * a.y + a.z * a.z + a.w * a.w;
    uint2 p;
    p.x = pack2bf(a.x, a.y);
    p.y = pack2bf(a.z, a.w);
    *(uint2*)(ob + col) = p;
  }
#pragma unroll
  for (int m = 1; m < 16; m <<= 1) dd += __shfl_xor(dd, m);
  if (t == 0) inv_nd[row] = 1.f / fmaxf(sqrtf(dd), EPSF);
}

// ---- staging helpers (addressing verbatim from r1/r2/r4, 0-conflict) -------
// B: full 512-row x 64-col bf16 tile via gload_lds, linear dest,
// inverse-swizzled source chunk (m173 pattern).
__device__ __forceinline__ void stage_B(unsigned char* Bsbuf,
                                        const unsigned short* __restrict__ Bb,
                                        int k0, int tid) {
#pragma unroll
  for (int j = 0; j < 8; ++j) {
    const int g   = j * 512 + tid;          // chunk 0..4095 (16 B each)
    const int row = g >> 3;                 // 8 chunks per 64-bf16 row
    const int sch = (g & 7) ^ (row & 7);    // inverse-swizzled source chunk
    gload_lds16(Bb + (size_t)row * D_ + k0 + (sch << 3), Bsbuf + (g << 4));
  }
}

// A+T: issue 4 float4 of c and 4 float4 of yt into regs (early issue).
__device__ __forceinline__ void load_AT(const float* __restrict__ Ab,
                                        const float* __restrict__ Tb,
                                        int k0, int tid,
                                        float4* va, float4* vb) {
#pragma unroll
  for (int j = 0; j < 4; ++j) {
    const int g   = j * 512 + tid;          // float4 0..2047
    const int row = g >> 4;                 // 16 float4 per 64-col row
    const int c4  = g & 15;
    const size_t off = (size_t)row * D_ + k0 + (c4 << 2);
    va[j] = *(const float4*)(Ab + off);
    vb[j] = *(const float4*)(Tb + off);
  }
}

// cvt + swizzled LDS write of A (r1-verified formula) + stats accumulate.
__device__ __forceinline__ void writeA_stats(unsigned char* As,
                                             const float4* va, const float4* vb,
                                             int tid,
                                             float* cc, float* tt, float* ct) {
#pragma unroll
  for (int j = 0; j < 4; ++j) {
    const int g   = j * 512 + tid;
    const int row = g >> 4;
    const int c4  = g & 15;
    const int off = (row << 7) + ((((c4 >> 1) ^ (row & 7))) << 4) + ((c4 & 1) << 3);
    uint2 pa;
    pa.x = pack2bf(va[j].x, va[j].y);
    pa.y = pack2bf(va[j].z, va[j].w);
    *(uint2*)(As + off) = pa;
    cc[j] += va[j].x * va[j].x + va[j].y * va[j].y + va[j].z * va[j].z + va[j].w * va[j].w;
    tt[j] += vb[j].x * vb[j].x + vb[j].y * vb[j].y + vb[j].z * vb[j].z + vb[j].w * vb[j].w;
    ct[j] += va[j].x * vb[j].x + va[j].y * vb[j].y + va[j].z * vb[j].z + va[j].w * vb[j].w;
  }
}

// ---------------------------------------------------------------------------
// Kernel B (r6): one block per (mt,b) = 128-row band x full N=512.
// - Bs double-buffered (2x64 KB): stage k+1 issued BEFORE compute k; the
//   vmcnt(0) drain at the end-of-iter barrier lands after a full MFMA phase
//   (T3 minimum-2-phase). r4/r5 serialized stage->drain->compute every iter.
// - Stats (inv_nc, rt) folded into A-staging: c read once, yt rides along,
//   register accumulators, reduced after the K-loop (no separate phase 1).
// - A single-buffered, T14 reg-split: loads early, cvt+ds_write in the short
//   two-barrier window.
// LDS: 16 + 128 + 2.5 KB = 146.5 KB -> 1 block/CU, 8 waves (accepted).
// ---------------------------------------------------------------------------
__launch_bounds__(512, 2)
__global__ void fused_ct(const float* __restrict__ c,
                         const float* __restrict__ yt,
                         const unsigned short* __restrict__ ydbf,
                         const float* __restrict__ inv_nd,
                         float* __restrict__ rt,
                         float* __restrict__ S) {
  __shared__ __align__(16) unsigned char As[128 * 64 * 2];       // 16 KB
  __shared__ __align__(16) unsigned char Bs[2][512 * 64 * 2];    // 2x64 KB
  __shared__ float s_invc[128];
  __shared__ float s_invd[512];

  const int mt = blockIdx.x;
  const int b  = blockIdx.y;
  const int tid  = threadIdx.x;
  const int lane = tid & 63;
  const int w    = tid >> 6;
  const int wm   = w >> 2, wn = w & 3;   // 2 x 4 waves over 128 x 512 out

  const float* Ab = c  + ((size_t)b * T_ + (size_t)mt * 128) * D_;
  const float* Tb = yt + ((size_t)b * T_ + (size_t)mt * 128) * D_;
  const unsigned short* Bb = ydbf + (size_t)b * N_ * D_;

  float4 va[4], vb[4];
  float cc[4] = {0.f, 0.f, 0.f, 0.f};
  float tt[4] = {0.f, 0.f, 0.f, 0.f};
  float ct[4] = {0.f, 0.f, 0.f, 0.f};

  // ---- prologue: iter-0 staging ----
  stage_B(Bs[0], Bb, 0, tid);            // async into Bs[0]
  load_AT(Ab, Tb, 0, tid, va, vb);       // c/yt regs (dependency-waited below)
  s_invd[tid] = inv_nd[b * N_ + tid];
  writeA_stats(As, va, vb, tid, cc, tt, ct);
  __syncthreads();                       // As visible; Bs[0] gloads drained

  f32x4 acc[4][8] = {};
  int cur = 0;

  // ---- K-loop: 8 iters of BK=64, double-buffered B ----
  for (int k0i = 0; k0i < 8; ++k0i) {
    const bool more = (k0i < 7);
    if (more) {
      load_AT(Ab, Tb, (k0i + 1) * 64, tid, va, vb);   // regs, early
      stage_B(Bs[cur ^ 1], Bb, (k0i + 1) * 64, tid);  // async, other buffer
    }

#pragma unroll
    for (int ks = 0; ks < 2; ++ks) {
      bf16x8 af[4], bfr[8];
#pragma unroll
      for (int i = 0; i < 4; ++i) {
        const int ar  = wm * 64 + i * 16 + (lane & 15);
        const int ach = (ks * 4 + (lane >> 4)) ^ (ar & 7);
        af[i] = *(const bf16x8*)(As + (ar << 7) + (ach << 4));
      }
#pragma unroll
      for (int n = 0; n < 8; ++n) {
        const int br  = wn * 128 + n * 16 + (lane & 15);
        const int bch = (ks * 4 + (lane >> 4)) ^ (br & 7);
        bfr[n] = *(const bf16x8*)(Bs[cur] + (br << 7) + (bch << 4));
      }
#pragma unroll
      for (int mi = 0; mi < 4; ++mi)
#pragma unroll
        for (int ni = 0; ni < 8; ++ni)
          acc[mi][ni] = __builtin_amdgcn_mfma_f32_16x16x32_bf16(
              af[mi], bfr[ni], acc[mi][ni], 0, 0, 0);
    }

    __syncthreads();   // all waves done reading As/Bs[cur]; drains k+1 gloads
    if (more) {
      writeA_stats(As, va, vb, tid, cc, tt, ct);  // short VALU+LDS window
      __syncthreads();                            // As(k+1) visible
    }
    cur ^= 1;
  }

  // ---- stats reduction (16-lane groups; thread t handles rows j*32+(tid>>4)) ----
#pragma unroll
  for (int j = 0; j < 4; ++j) {
#pragma unroll
    for (int m = 1; m < 16; m <<= 1) {
      cc[j] += __shfl_xor(cc[j], m);
      tt[j] += __shfl_xor(tt[j], m);
      ct[j] += __shfl_xor(ct[j], m);
    }
    if ((tid & 15) == 0) {
      const int row = j * 32 + (tid >> 4);
      const float nc = fmaxf(sqrtf(cc[j]), EPSF);
      const float nt = fmaxf(sqrtf(tt[j]), EPSF);
      s_invc[row] = 1.f / nc;
      rt[b * T_ + mt * 128 + row] = ct[j] / (nt * nc);
    }
  }
  __syncthreads();

  // ---- epilogue: exp(acc*invc*invd) row-sum over all 512 cols ----
  float invd[8];
#pragma unroll
  for (int ni = 0; ni < 8; ++ni)
    invd[ni] = s_invd[wn * 128 + ni * 16 + (lane & 15)];

#pragma unroll
  for (int mi = 0; mi < 4; ++mi) {
    const int t0l = wm * 64 + mi * 16 + ((lane >> 4) << 2);  // local row
#pragma unroll
    for (int r = 0; r < 4; ++r) {
      const float invc = s_invc[t0l + r];
      float s = 0.f;
#pragma unroll
      for (int ni = 0; ni < 8; ++ni)
        s += __expf(acc[mi][ni][r] * invc * invd[ni]);
      s += __shfl_xor(s, 1);
      s += __shfl_xor(s, 2);
      s += __shfl_xor(s, 4);
      s += __shfl_xor(s, 8);
      if ((lane & 15) == 0)
        atomicAdd(&S[b * T_ + mt * 128 + t0l + r], s);
    }
  }
}

// ---------------------------------------------------------------------------
// Kernel C: loss = sum_{b,t} log(S + exp(r_t)) - r_t
// ---------------------------------------------------------------------------
__global__ void final_loss(const float* __restrict__ S,
                           const float* __restrict__ rt,
                           float* __restrict__ out) {
  const int tid = threadIdx.x;
  float sum = 0.f;
  for (int i = blockIdx.x * blockDim.x + tid; i < B_ * T_;
       i += gridDim.x * blockDim.x) {
    const float r = rt[i];
    sum += logf(S[i] + __expf(r)) - r;
  }
#pragma unroll
  for (int m = 32; m; m >>= 1) sum += __shfl_xor(sum, m);
  __shared__ float ws[4];
  if ((tid & 63) == 0) ws[tid >> 6] = sum;
  __syncthreads();
  if (tid == 0) atomicAdd(out, ws[0] + ws[1] + ws[2] + ws[3]);
}

// ---------------------------------------------------------------------------
extern "C" void kernel_launch(void* const* d_in, const int* in_sizes, int n_in,
                              void* d_out, int out_size, void* d_ws, size_t ws_size,
                              hipStream_t stream) {
  (void)in_sizes; (void)n_in; (void)out_size; (void)ws_size;
  const float* c  = (const float*)d_in[0];
  const float* yt = (const float*)d_in[1];
  const float* yd = (const float*)d_in[2];
  float* out = (float*)d_out;

  // ws layout: [ydbf: B*N*D u16][rt: B*T f][inv_nd: B*N f][S: B*T f]
  const size_t ydbf_n = (size_t)B_ * N_ * D_;   // 4.2M u16 = 8 MiB
  unsigned short* ydbf = (unsigned short*)d_ws;
  float* rt     = (float*)(ydbf + ydbf_n);      // B*T
  float* inv_nd = rt + B_ * T_;                 // B*N
  float* S      = inv_nd + B_ * N_;             // B*T

  hipMemsetAsync(S, 0, (size_t)B_ * T_ * sizeof(float), stream);
  hipMemsetAsync(out, 0, sizeof(float), stream);

  rownorms_d<<<B_ * N_ / 16, 256, 0, stream>>>(yd, inv_nd, ydbf);

  dim3 gF(T_ / 128, B_);   // (32, 16) = 512 blocks, 512 threads
  fused_ct<<<gF, 512, 0, stream>>>(c, yt, ydbf, inv_nd, rt, S);

  final_loss<<<64, 256, 0, stream>>>(S, rt, out);
}